// Round 5
// baseline (466.820 us; speedup 1.0000x reference)
//
#include <hip/hip_runtime.h>

#define NHEADS 16
#define TSEQ   2048
#define BATCH  4
#define SC2F   0.18033688011112042f   // 0.125 * log2(e)

typedef float f32x4 __attribute__((ext_vector_type(4)));
typedef short bf16x8 __attribute__((ext_vector_type(8)));

__device__ __forceinline__ unsigned short f2bf(float f){
  unsigned int u = __builtin_bit_cast(unsigned int, f);
  u += 0x7fff + ((u >> 16) & 1);
  return (unsigned short)(u >> 16);
}

__device__ __forceinline__ unsigned int cvtpk(float lo, float hi){
  unsigned int r;
  asm("v_cvt_pk_bf16_f32 %0, %1, %2" : "=v"(r) : "v"(lo), "v"(hi));
  return r;
}

__device__ __forceinline__ f32x4 zero4(){ f32x4 z; z[0]=0.f; z[1]=0.f; z[2]=0.f; z[3]=0.f; return z; }

__device__ __forceinline__ f32x4 mfma16(bf16x8 a, bf16x8 b, f32x4 c){
  return __builtin_amdgcn_mfma_f32_16x16x32_bf16(a, b, c, 0, 0, 0);
}

__device__ __forceinline__ void async_copy16(void* lds, const void* g){
  __builtin_amdgcn_global_load_lds(
      (const __attribute__((address_space(1))) unsigned int*)g,
      (__attribute__((address_space(3))) unsigned int*)lds, 16, 0, 0);
}

// ---------------- LayerNorm + bf16 cast: x[8192][1024] f32 -> hb bf16 ----------------
__global__ __launch_bounds__(256) void ln_kernel(
    const float* __restrict__ x, const float* __restrict__ gw,
    const float* __restrict__ bw, unsigned short* __restrict__ hb){
  const int row = blockIdx.x;
  const int t = threadIdx.x;
  const float* xr = x + (size_t)row * 1024;
  f32x4 v = *(const f32x4*)(xr + t*4);
  float s  = v[0]+v[1]+v[2]+v[3];
  float s2 = v[0]*v[0]+v[1]*v[1]+v[2]*v[2]+v[3]*v[3];
  #pragma unroll
  for(int off=1; off<64; off<<=1){
    s  += __shfl_xor(s,  off);
    s2 += __shfl_xor(s2, off);
  }
  __shared__ float red[8];
  const int wid = t>>6, lane = t&63;
  if(lane==0){ red[wid]=s; red[4+wid]=s2; }
  __syncthreads();
  float ts  = red[0]+red[1]+red[2]+red[3];
  float ts2 = red[4]+red[5]+red[6]+red[7];
  float mu = ts * (1.0f/1024.0f);
  float rs = rsqrtf(ts2*(1.0f/1024.0f) - mu*mu + 1e-5f);
  f32x4 gv = *(const f32x4*)(gw + t*4);
  f32x4 bv = *(const f32x4*)(bw + t*4);
  ushort4 o;
  o.x = f2bf((v[0]-mu)*rs*gv[0] + bv[0]);
  o.y = f2bf((v[1]-mu)*rs*gv[1] + bv[1]);
  o.z = f2bf((v[2]-mu)*rs*gv[2] + bv[2]);
  o.w = f2bf((v[3]-mu)*rs*gv[3] + bv[3]);
  *(ushort4*)(hb + (size_t)row*1024 + t*4) = o;
}

// ---------------- Pack Wq,Wk,Wv,Wo (f32 [1024][1024] each) -> bf16 [4096][1024] ----------------
__global__ __launch_bounds__(256) void prep_w(
    const float* __restrict__ Wq, const float* __restrict__ Wk,
    const float* __restrict__ Wv, const float* __restrict__ Wo,
    unsigned short* __restrict__ wpack){
  int i = (blockIdx.x*256 + threadIdx.x) * 4;
  int sel = i >> 20;
  const float* src = sel==0 ? Wq : sel==1 ? Wk : sel==2 ? Wv : Wo;
  int off = i & ((1<<20)-1);
  f32x4 v = *(const f32x4*)(src + off);
  ushort4 o;
  o.x=f2bf(v[0]); o.y=f2bf(v[1]); o.z=f2bf(v[2]); o.w=f2bf(v[3]);
  *(ushort4*)(wpack + i) = o;
}

// ---------------- Pack bias [3072] f32 + mask-bias [8192] f32 ----------------
__global__ __launch_bounds__(256) void prep2(
    const float* __restrict__ bq, const float* __restrict__ bk, const float* __restrict__ bv,
    const int* __restrict__ amask, float* __restrict__ biaspack, float* __restrict__ mbias){
  int i = blockIdx.x*256 + threadIdx.x;
  if(i < 3072){
    biaspack[i] = (i < 1024) ? bq[i] : (i < 2048) ? bk[i-1024] : bv[i-2048];
  }
  if(i < 8192){
    mbias[i] = amask[i] ? 0.0f : -1e30f;   // additive bias in log2 units
  }
}

// ---------------- bt-GEMM, 128x128 tile, BK=64, global_load_lds (m97 structure) ----------------
template<int OUT_MODE>
__global__ __launch_bounds__(256) void gemm_bt(
    const unsigned short* __restrict__ A, const unsigned short* __restrict__ Bt,
    const float* __restrict__ bias, const float* __restrict__ resid,
    void* __restrict__ out, int N){
  __shared__ __align__(16) unsigned short As[128*64];
  __shared__ __align__(16) unsigned short Bs[128*64];
  const int tid = threadIdx.x;
  const int w = tid>>6, lane = tid&63;
  const int wr = w>>1, wc = w&1;
  const int la = lane&15, g = lane>>4;
  const int brow = blockIdx.y*128, bcol = blockIdx.x*128;

  f32x4 acc[4][4];
  #pragma unroll
  for(int mi=0;mi<4;mi++)
    #pragma unroll
    for(int ni=0;ni<4;ni++) acc[mi][ni] = zero4();

  const char* Ag = (const char*)(A + (size_t)brow*1024);
  const char* Bg = (const char*)(Bt + (size_t)bcol*1024);

  for(int kt=0; kt<1024; kt+=64){
    #pragma unroll
    for(int r=0;r<4;r++){
      int o = tid*16 + r*4096;
      int row = o >> 7;
      int cb  = o & 127;
      async_copy16((char*)As + o, Ag + (size_t)row*2048 + (size_t)kt*2 + cb);
      async_copy16((char*)Bs + o, Bg + (size_t)row*2048 + (size_t)kt*2 + cb);
    }
    __syncthreads();
    #pragma unroll
    for(int kk=0;kk<2;kk++){
      bf16x8 af[4], bf[4];
      #pragma unroll
      for(int mi=0;mi<4;mi++)
        af[mi] = *(const bf16x8*)((char*)As + (size_t)(wr*64+mi*16+la)*128 + kk*64 + g*16);
      #pragma unroll
      for(int ni=0;ni<4;ni++)
        bf[ni] = *(const bf16x8*)((char*)Bs + (size_t)(wc*64+ni*16+la)*128 + kk*64 + g*16);
      #pragma unroll
      for(int mi=0;mi<4;mi++)
        #pragma unroll
        for(int ni=0;ni<4;ni++)
          acc[mi][ni] = mfma16(af[mi], bf[ni], acc[mi][ni]);
    }
    __syncthreads();
  }

  const int orow = brow + wr*64, ocol = bcol + wc*64;
  if(OUT_MODE == 0){
    unsigned short* ob = (unsigned short*)out;
    #pragma unroll
    for(int mi=0;mi<4;mi++){
      #pragma unroll
      for(int ni=0;ni<4;ni++){
        int row = orow + mi*16 + g*4;
        int col = ocol + ni*16 + la;
        float bsv = bias[col];
        #pragma unroll
        for(int r=0;r<4;r++)
          ob[(size_t)(row+r)*N + col] = f2bf(acc[mi][ni][r] + bsv);
      }
    }
  } else {
    float* of = (float*)out;
    #pragma unroll
    for(int mi=0;mi<4;mi++){
      #pragma unroll
      for(int ni=0;ni<4;ni++){
        int row = orow + mi*16 + g*4;
        int col = ocol + ni*16 + la;
        float bsv = bias[col];
        #pragma unroll
        for(int r=0;r<4;r++){
          size_t idx = (size_t)(row+r)*N + col;
          of[idx] = resid[idx] + acc[mi][ni][r] + bsv;
        }
      }
    }
  }
}

// ---------------- V transpose: qkv v-part -> vt[bh][d][t] ----------------
__global__ __launch_bounds__(256) void vtrans(
    const unsigned short* __restrict__ qkv, unsigned short* __restrict__ vt){
  __shared__ unsigned int tile32[64][37];
  const int tid = threadIdx.x;
  const int bh = blockIdx.y;
  const int b = bh >> 4, h = bh & 15;
  const int tb = blockIdx.x * 64;
  #pragma unroll
  for(int r=0;r<2;r++){
    int trow = (tid>>3) + r*32;
    int d0   = (tid&7)*8;
    uint4 v = *(const uint4*)(qkv + (size_t)(b*TSEQ + tb + trow)*3072 + 2048 + h*64 + d0);
    unsigned int* dst = &tile32[trow][(tid&7)*4];
    dst[0]=v.x; dst[1]=v.y; dst[2]=v.z; dst[3]=v.w;
  }
  __syncthreads();
  const unsigned short* t16 = (const unsigned short*)&tile32[0][0];
  #pragma unroll
  for(int r=0;r<2;r++){
    int d  = (tid>>3) + r*32;
    int t0 = (tid&7)*8;
    unsigned short tmp[8];
    #pragma unroll
    for(int j=0;j<8;j++) tmp[j] = t16[(size_t)(t0+j)*74 + d];
    uint4 o;
    o.x = tmp[0] | ((unsigned)tmp[1]<<16);
    o.y = tmp[2] | ((unsigned)tmp[3]<<16);
    o.z = tmp[4] | ((unsigned)tmp[5]<<16);
    o.w = tmp[6] | ((unsigned)tmp[7]<<16);
    *(uint4*)(vt + (size_t)(bh*64 + d)*TSEQ + tb + t0) = o;
  }
}

// ---------------- Flash attention v5: 40KB LDS (4 blocks/CU), raw v_exp, tree reductions ----
// Swizzle discipline (rule #21): rows of 128B = 8 slots of 16B; physical_slot =
// linear_slot ^ (row&7) on stage-source, P-write and all reads (same involution).
__global__ __launch_bounds__(256, 4) void attn_kernel(
    const unsigned short* __restrict__ qkv,   // [8192][3072] bf16 (q|k|v)
    const unsigned short* __restrict__ vt,    // [64][64][2048] bf16 (V^T per bh)
    const float* __restrict__ mbias,          // [8192] additive mask bias (log2 units)
    unsigned short* __restrict__ cout){       // [8192][1024] bf16
  __shared__ __align__(16) unsigned short ksm[2][64*64];   // K dbuf, 2x8KB
  __shared__ __align__(16) unsigned short vsm[2][64*64];   // V^T dbuf, 2x8KB
  __shared__ __align__(16) unsigned short ptile[4][16*64]; // per-wave P (one q-half), 8KB

  const int tid = threadIdx.x;
  const int w = tid>>6, lane = tid&63;
  const int qv = lane&15, g = lane>>4;
  const int bh = blockIdx.x;
  const int b = bh>>4, h = bh&15;
  const int qb = blockIdx.y*128;

  // Q fragments: q rows w*32 + t*16 + qv, d = ksi*32 + g*8 + j
  bf16x8 qf[2][2];
  #pragma unroll
  for(int t=0;t<2;t++){
    const unsigned short* qp = qkv + (size_t)(b*TSEQ + qb + w*32 + t*16 + qv)*3072 + h*64 + g*8;
    qf[t][0] = *(const bf16x8*)qp;
    qf[t][1] = *(const bf16x8*)(qp + 32);
  }

  f32x4 oacc[4][2];
  #pragma unroll
  for(int mi=0;mi<4;mi++){ oacc[mi][0]=zero4(); oacc[mi][1]=zero4(); }
  float m2[2]   = {-1e30f, -1e30f};   // running max (log2 units)
  float lsum[2] = {0.f, 0.f};         // per-lane partial sums (reduced at end)

  // staging pointers (strength-reduced; advance per kt)
  const int srow  = lane>>3;
  const int sslot = (lane&7) ^ srow;
  const unsigned short* kgp = qkv + (size_t)b*TSEQ*3072 + 1024 + h*64
                              + (size_t)(w*8+srow)*3072 + sslot*8;
  const unsigned short* vgp = vt + (size_t)bh*64*TSEQ
                              + (size_t)(w*8+srow)*2048 + sslot*8;
  char* kd = (char*)ksm + w*1024 + lane*16;
  char* vd = (char*)vsm + w*1024 + lane*16;
  const float* mbp = mbias + (size_t)b*TSEQ + g*4;

  // read-side swizzle constants
  const int c3    = qv & 7;
  const int phys0 = (g ^ c3) << 4;           // linear slot ksi*4+g -> phys0 ^ (ksi<<6)
  const int pC    = (g>>1) ^ c3;             // P-write slot kk*2+(g>>1) -> ((kk*2)^pC)<<4
  char*       pWb = (char*)&ptile[w][0] + qv*128 + (g&1)*8;
  const char* pRb = (const char*)&ptile[w][0] + qv*128;

#define STAGE(buf)                                                    \
  { _Pragma("unroll")                                                 \
    for(int r_=0;r_<2;r_++){                                          \
      async_copy16(kd + (buf)*8192 + r_*4096, kgp + r_*98304);        \
      async_copy16(vd + (buf)*8192 + r_*4096, vgp + r_*65536);        \
    }                                                                 \
    kgp += 196608; vgp += 64; }

  STAGE(0);
  int cur = 0;

  for(int kt=0; kt<TSEQ/64; kt++){
    __syncthreads();                 // drains vmcnt(0): buf[cur] ready
    if(kt < TSEQ/64 - 1) STAGE(cur^1);   // prefetch overlaps this kt's compute

    f32x4 mbv[4];
    #pragma unroll
    for(int kk=0;kk<4;kk++) mbv[kk] = *(const f32x4*)(mbp + kk*16);
    mbp += 64;

    const char* kT = (const char*)ksm + cur*8192 + qv*128;
    const char* vT = (const char*)vsm + cur*8192 + qv*128;

    // K fragments once per kt, shared across both q-halves
    bf16x8 kf[2][4];
    #pragma unroll
    for(int ksi=0;ksi<2;ksi++)
      #pragma unroll
      for(int kk=0;kk<4;kk++)
        kf[ksi][kk] = *(const bf16x8*)(kT + kk*2048 + (phys0 ^ (ksi<<6)));

    #pragma unroll
    for(int t=0;t<2;t++){
      // S^T[key][q] = K · Q^T
      f32x4 s[4];
      #pragma unroll
      for(int kk=0;kk<4;kk++) s[kk]=zero4();
      __builtin_amdgcn_s_setprio(1);
      #pragma unroll
      for(int ksi=0;ksi<2;ksi++)
        #pragma unroll
        for(int kk=0;kk<4;kk++)
          s[kk] = mfma16(kf[ksi][kk], qf[t][ksi], s[kk]);
      __builtin_amdgcn_s_setprio(0);

      // softmax (log2 domain), in-place scale+bias, tree max
      #pragma unroll
      for(int kk=0;kk<4;kk++)
        #pragma unroll
        for(int r=0;r<4;r++)
          s[kk][r] = s[kk][r]*SC2F + mbv[kk][r];

      f32x4 mx;
      #pragma unroll
      for(int r=0;r<4;r++)
        mx[r] = fmaxf(fmaxf(s[0][r], s[1][r]), fmaxf(s[2][r], s[3][r]));
      float pm = fmaxf(fmaxf(mx[0], mx[1]), fmaxf(mx[2], mx[3]));
      pm = fmaxf(pm, __shfl_xor(pm, 16));
      pm = fmaxf(pm, __shfl_xor(pm, 32));

      float m2t = m2[t];
      if(!__all(pm - m2t <= 8.0f)){          // defer-max (T13, THR=8)
        float mn = fmaxf(m2t, pm);
        float sf = __builtin_amdgcn_exp2f(m2t - mn);
        lsum[t] *= sf;
        #pragma unroll
        for(int mi=0;mi<4;mi++){
          #pragma unroll
          for(int r=0;r<4;r++) oacc[mi][t][r] *= sf;
        }
        m2t = mn; m2[t] = mn;
      }

      float ps = 0.f;
      #pragma unroll
      for(int kk=0;kk<4;kk++){
        float p0 = __builtin_amdgcn_exp2f(s[kk][0]-m2t);
        float p1 = __builtin_amdgcn_exp2f(s[kk][1]-m2t);
        float p2 = __builtin_amdgcn_exp2f(s[kk][2]-m2t);
        float p3 = __builtin_amdgcn_exp2f(s[kk][3]-m2t);
        ps += (p0+p1)+(p2+p3);
        uint2 wv; wv.x = cvtpk(p0, p1); wv.y = cvtpk(p2, p3);
        *(uint2*)(pWb + (((kk*2) ^ pC) << 4)) = wv;
      }
      lsum[t] += ps;                         // cross-lane reduce deferred to epilogue

      asm volatile("" ::: "memory");   // order in-wave P writes before P reads

      // O^T[d][q] += V^T · P^T for this q-half
      __builtin_amdgcn_s_setprio(1);
      #pragma unroll
      for(int ksi=0;ksi<2;ksi++){
        bf16x8 pb = *(const bf16x8*)(pRb + (phys0 ^ (ksi<<6)));
        #pragma unroll
        for(int mi=0;mi<4;mi++){
          bf16x8 av = *(const bf16x8*)(vT + mi*2048 + (phys0 ^ (ksi<<6)));
          oacc[mi][t] = mfma16(av, pb, oacc[mi][t]);
        }
      }
      __builtin_amdgcn_s_setprio(0);
      asm volatile("" ::: "memory");   // order P reads before next half's P writes
    }
    cur ^= 1;
  }
#undef STAGE

  #pragma unroll
  for(int t=0;t<2;t++){
    float l = lsum[t];
    l += __shfl_xor(l, 16);
    l += __shfl_xor(l, 32);
    float inv = 1.0f / l;
    unsigned short* crow = cout + (size_t)(b*TSEQ + qb + w*32 + t*16 + qv)*1024 + h*64;
    #pragma unroll
    for(int mi=0;mi<4;mi++){
      uint2 o;
      o.x = cvtpk(oacc[mi][t][0]*inv, oacc[mi][t][1]*inv);
      o.y = cvtpk(oacc[mi][t][2]*inv, oacc[mi][t][3]*inv);
      *(uint2*)(crow + mi*16 + g*4) = o;
    }
  }
}

extern "C" void kernel_launch(void* const* d_in, const int* in_sizes, int n_in,
                              void* d_out, int out_size, void* d_ws, size_t ws_size,
                              hipStream_t stream){
  const float* x    = (const float*)d_in[0];
  const int*   am   = (const int*)  d_in[1];
  const float* ln_g = (const float*)d_in[2];
  const float* ln_b = (const float*)d_in[3];
  const float* Wq   = (const float*)d_in[4];
  const float* bq   = (const float*)d_in[5];
  const float* Wk   = (const float*)d_in[6];
  const float* bk   = (const float*)d_in[7];
  const float* Wv   = (const float*)d_in[8];
  const float* bv   = (const float*)d_in[9];
  const float* Wo   = (const float*)d_in[10];
  const float* bo   = (const float*)d_in[11];
  float* out = (float*)d_out;

  char* ws = (char*)d_ws;
  unsigned short* hb       = (unsigned short*)(ws);                         // 16MB
  unsigned short* wpack    = (unsigned short*)(ws + ((size_t)16<<20));      // 8MB
  float*          biaspack = (float*)         (ws + ((size_t)24<<20));      // 12KB
  float*          mbias    = (float*)         (ws + ((size_t)24<<20) + (64<<10)); // 32KB
  unsigned short* qkv      = (unsigned short*)(ws + ((size_t)25<<20));      // 48MB
  unsigned short* vt       = (unsigned short*)(ws + ((size_t)73<<20));      // 16MB

  ln_kernel<<<8192, 256, 0, stream>>>(x, ln_g, ln_b, hb);
  prep_w  <<<4096, 256, 0, stream>>>(Wq, Wk, Wv, Wo, wpack);
  prep2   <<<32,   256, 0, stream>>>(bq, bk, bv, am, biaspack, mbias);
  gemm_bt<0><<<dim3(24,64), 256, 0, stream>>>(hb, wpack, biaspack, nullptr, qkv, 3072);
  vtrans  <<<dim3(32,64), 256, 0, stream>>>(qkv, vt);
  attn_kernel<<<dim3(64,16), 256, 0, stream>>>(qkv, vt, mbias, hb);
  gemm_bt<1><<<dim3(8,64), 256, 0, stream>>>(hb, wpack + ((size_t)3<<20), bo, x, out, 1024);
}

// Round 8
// 362.903 us; speedup vs baseline: 1.2863x; 1.2863x over previous
//
#include <hip/hip_runtime.h>

#define NHEADS 16
#define TSEQ   2048
#define BATCH  4
#define SC2F   0.18033688011112042f   // 0.125 * log2(e)

typedef float f32x4 __attribute__((ext_vector_type(4)));
typedef short bf16x8 __attribute__((ext_vector_type(8)));

__device__ __forceinline__ unsigned short f2bf(float f){
  unsigned int u = __builtin_bit_cast(unsigned int, f);
  u += 0x7fff + ((u >> 16) & 1);
  return (unsigned short)(u >> 16);
}

__device__ __forceinline__ unsigned int cvtpk(float lo, float hi){
  unsigned int r;
  asm("v_cvt_pk_bf16_f32 %0, %1, %2" : "=v"(r) : "v"(lo), "v"(hi));
  return r;
}

__device__ __forceinline__ f32x4 zero4(){ f32x4 z; z[0]=0.f; z[1]=0.f; z[2]=0.f; z[3]=0.f; return z; }

__device__ __forceinline__ f32x4 mfma16(bf16x8 a, bf16x8 b, f32x4 c){
  return __builtin_amdgcn_mfma_f32_16x16x32_bf16(a, b, c, 0, 0, 0);
}

__device__ __forceinline__ void async_copy16(void* lds, const void* g){
  __builtin_amdgcn_global_load_lds(
      (const __attribute__((address_space(1))) unsigned int*)g,
      (__attribute__((address_space(3))) unsigned int*)lds, 16, 0, 0);
}

// ---------------- LayerNorm + bf16 cast: x[8192][1024] f32 -> hb bf16 ----------------
__global__ __launch_bounds__(256) void ln_kernel(
    const float* __restrict__ x, const float* __restrict__ gw,
    const float* __restrict__ bw, unsigned short* __restrict__ hb){
  const int row = blockIdx.x;
  const int t = threadIdx.x;
  const float* xr = x + (size_t)row * 1024;
  f32x4 v = *(const f32x4*)(xr + t*4);
  float s  = v[0]+v[1]+v[2]+v[3];
  float s2 = v[0]*v[0]+v[1]*v[1]+v[2]*v[2]+v[3]*v[3];
  #pragma unroll
  for(int off=1; off<64; off<<=1){
    s  += __shfl_xor(s,  off);
    s2 += __shfl_xor(s2, off);
  }
  __shared__ float red[8];
  const int wid = t>>6, lane = t&63;
  if(lane==0){ red[wid]=s; red[4+wid]=s2; }
  __syncthreads();
  float ts  = red[0]+red[1]+red[2]+red[3];
  float ts2 = red[4]+red[5]+red[6]+red[7];
  float mu = ts * (1.0f/1024.0f);
  float rs = rsqrtf(ts2*(1.0f/1024.0f) - mu*mu + 1e-5f);
  f32x4 gv = *(const f32x4*)(gw + t*4);
  f32x4 bv = *(const f32x4*)(bw + t*4);
  ushort4 o;
  o.x = f2bf((v[0]-mu)*rs*gv[0] + bv[0]);
  o.y = f2bf((v[1]-mu)*rs*gv[1] + bv[1]);
  o.z = f2bf((v[2]-mu)*rs*gv[2] + bv[2]);
  o.w = f2bf((v[3]-mu)*rs*gv[3] + bv[3]);
  *(ushort4*)(hb + (size_t)row*1024 + t*4) = o;
}

// ---------------- Pack Wq,Wk,Wv,Wo (f32 [1024][1024] each) -> bf16 [4096][1024] ----------------
__global__ __launch_bounds__(256) void prep_w(
    const float* __restrict__ Wq, const float* __restrict__ Wk,
    const float* __restrict__ Wv, const float* __restrict__ Wo,
    unsigned short* __restrict__ wpack){
  int i = (blockIdx.x*256 + threadIdx.x) * 4;
  int sel = i >> 20;
  const float* src = sel==0 ? Wq : sel==1 ? Wk : sel==2 ? Wv : Wo;
  int off = i & ((1<<20)-1);
  f32x4 v = *(const f32x4*)(src + off);
  ushort4 o;
  o.x=f2bf(v[0]); o.y=f2bf(v[1]); o.z=f2bf(v[2]); o.w=f2bf(v[3]);
  *(ushort4*)(wpack + i) = o;
}

// ---------------- Pack bias [3072] f32 + mask-bias [8192] f32 ----------------
__global__ __launch_bounds__(256) void prep2(
    const float* __restrict__ bq, const float* __restrict__ bk, const float* __restrict__ bv,
    const int* __restrict__ amask, float* __restrict__ biaspack, float* __restrict__ mbias){
  int i = blockIdx.x*256 + threadIdx.x;
  if(i < 3072){
    biaspack[i] = (i < 1024) ? bq[i] : (i < 2048) ? bk[i-1024] : bv[i-2048];
  }
  if(i < 8192){
    mbias[i] = amask[i] ? 0.0f : -1e30f;   // additive bias in log2 units
  }
}

// ---------------- bt-GEMM, 128x128 tile, BK=64, global_load_lds + XCD tile swizzle ----------
template<int OUT_MODE>
__global__ __launch_bounds__(256) void gemm_bt(
    const unsigned short* __restrict__ A, const unsigned short* __restrict__ Bt,
    const float* __restrict__ bias, const float* __restrict__ resid,
    void* __restrict__ out, int N){
  __shared__ __align__(16) unsigned short As[128*64];
  __shared__ __align__(16) unsigned short Bs[128*64];
  const int tid = threadIdx.x;
  const int w = tid>>6, lane = tid&63;
  const int wr = w>>1, wc = w&1;
  const int la = lane&15, g = lane>>4;

  // XCD-aware tile swizzle (T1): nwg % 8 == 0 for both call sites -> bijective.
  // XCD x (orig%8==x) executes a contiguous tile range -> A-panel reuse in its L2.
  const int nwg  = gridDim.x * gridDim.y;
  const int orig = blockIdx.y * gridDim.x + blockIdx.x;
  const int swz  = (orig & 7) * (nwg >> 3) + (orig >> 3);
  const int brow = (swz / gridDim.x) * 128, bcol = (swz % gridDim.x) * 128;

  f32x4 acc[4][4];
  #pragma unroll
  for(int mi=0;mi<4;mi++)
    #pragma unroll
    for(int ni=0;ni<4;ni++) acc[mi][ni] = zero4();

  const char* Ag = (const char*)(A + (size_t)brow*1024);
  const char* Bg = (const char*)(Bt + (size_t)bcol*1024);

  for(int kt=0; kt<1024; kt+=64){
    #pragma unroll
    for(int r=0;r<4;r++){
      int o = tid*16 + r*4096;
      int row = o >> 7;
      int cb  = o & 127;
      async_copy16((char*)As + o, Ag + (size_t)row*2048 + (size_t)kt*2 + cb);
      async_copy16((char*)Bs + o, Bg + (size_t)row*2048 + (size_t)kt*2 + cb);
    }
    __syncthreads();
    #pragma unroll
    for(int kk=0;kk<2;kk++){
      bf16x8 af[4], bf[4];
      #pragma unroll
      for(int mi=0;mi<4;mi++)
        af[mi] = *(const bf16x8*)((char*)As + (size_t)(wr*64+mi*16+la)*128 + kk*64 + g*16);
      #pragma unroll
      for(int ni=0;ni<4;ni++)
        bf[ni] = *(const bf16x8*)((char*)Bs + (size_t)(wc*64+ni*16+la)*128 + kk*64 + g*16);
      #pragma unroll
      for(int mi=0;mi<4;mi++)
        #pragma unroll
        for(int ni=0;ni<4;ni++)
          acc[mi][ni] = mfma16(af[mi], bf[ni], acc[mi][ni]);
    }
    __syncthreads();
  }

  const int orow = brow + wr*64, ocol = bcol + wc*64;
  if(OUT_MODE == 0){
    unsigned short* ob = (unsigned short*)out;
    #pragma unroll
    for(int mi=0;mi<4;mi++){
      #pragma unroll
      for(int ni=0;ni<4;ni++){
        int row = orow + mi*16 + g*4;
        int col = ocol + ni*16 + la;
        float bsv = bias[col];
        #pragma unroll
        for(int r=0;r<4;r++)
          ob[(size_t)(row+r)*N + col] = f2bf(acc[mi][ni][r] + bsv);
      }
    }
  } else {
    float* of = (float*)out;
    #pragma unroll
    for(int mi=0;mi<4;mi++){
      #pragma unroll
      for(int ni=0;ni<4;ni++){
        int row = orow + mi*16 + g*4;
        int col = ocol + ni*16 + la;
        float bsv = bias[col];
        #pragma unroll
        for(int r=0;r<4;r++){
          size_t idx = (size_t)(row+r)*N + col;
          of[idx] = resid[idx] + acc[mi][ni][r] + bsv;
        }
      }
    }
  }
}

// ---------------- V transpose: qkv v-part -> vt[bh][d][t] ----------------
__global__ __launch_bounds__(256) void vtrans(
    const unsigned short* __restrict__ qkv, unsigned short* __restrict__ vt){
  __shared__ unsigned int tile32[64][37];
  const int tid = threadIdx.x;
  const int bh = blockIdx.y;
  const int b = bh >> 4, h = bh & 15;
  const int tb = blockIdx.x * 64;
  #pragma unroll
  for(int r=0;r<2;r++){
    int trow = (tid>>3) + r*32;
    int d0   = (tid&7)*8;
    uint4 v = *(const uint4*)(qkv + (size_t)(b*TSEQ + tb + trow)*3072 + 2048 + h*64 + d0);
    unsigned int* dst = &tile32[trow][(tid&7)*4];
    dst[0]=v.x; dst[1]=v.y; dst[2]=v.z; dst[3]=v.w;
  }
  __syncthreads();
  const unsigned short* t16 = (const unsigned short*)&tile32[0][0];
  #pragma unroll
  for(int r=0;r<2;r++){
    int d  = (tid>>3) + r*32;
    int t0 = (tid&7)*8;
    unsigned short tmp[8];
    #pragma unroll
    for(int j=0;j<8;j++) tmp[j] = t16[(size_t)(t0+j)*74 + d];
    uint4 o;
    o.x = tmp[0] | ((unsigned)tmp[1]<<16);
    o.y = tmp[2] | ((unsigned)tmp[3]<<16);
    o.z = tmp[4] | ((unsigned)tmp[5]<<16);
    o.w = tmp[6] | ((unsigned)tmp[7]<<16);
    *(uint4*)(vt + (size_t)(bh*64 + d)*TSEQ + tb + t0) = o;
  }
}

// ---------------- Flash attention v6: 40KB LDS, natural VGPR (no spills), raw v_exp ----------
// Swizzle discipline (rule #21): rows of 128B = 8 slots of 16B; physical_slot =
// linear_slot ^ (row&7) on stage-source, P-write and all reads (same involution).
// NOTE: plain __launch_bounds__(256) — pinning (256,4) forced VGPR=64 and spilled
// the accumulators to scratch (r5: WRITE_SIZE 16->184MB, attn 175->251us).
__global__ __launch_bounds__(256) void attn_kernel(
    const unsigned short* __restrict__ qkv,   // [8192][3072] bf16 (q|k|v)
    const unsigned short* __restrict__ vt,    // [64][64][2048] bf16 (V^T per bh)
    const float* __restrict__ mbias,          // [8192] additive mask bias (log2 units)
    unsigned short* __restrict__ cout){       // [8192][1024] bf16
  __shared__ __align__(16) unsigned short ksm[2][64*64];   // K dbuf, 2x8KB
  __shared__ __align__(16) unsigned short vsm[2][64*64];   // V^T dbuf, 2x8KB
  __shared__ __align__(16) unsigned short ptile[4][16*64]; // per-wave P (one q-half), 8KB

  const int tid = threadIdx.x;
  const int w = tid>>6, lane = tid&63;
  const int qv = lane&15, g = lane>>4;
  const int bh = blockIdx.x;
  const int b = bh>>4, h = bh&15;
  const int qb = blockIdx.y*128;

  // Q fragments: q rows w*32 + t*16 + qv, d = ksi*32 + g*8 + j
  bf16x8 qf[2][2];
  #pragma unroll
  for(int t=0;t<2;t++){
    const unsigned short* qp = qkv + (size_t)(b*TSEQ + qb + w*32 + t*16 + qv)*3072 + h*64 + g*8;
    qf[t][0] = *(const bf16x8*)qp;
    qf[t][1] = *(const bf16x8*)(qp + 32);
  }

  f32x4 oacc[4][2];
  #pragma unroll
  for(int mi=0;mi<4;mi++){ oacc[mi][0]=zero4(); oacc[mi][1]=zero4(); }
  float m2[2]   = {-1e30f, -1e30f};   // running max (log2 units)
  float lsum[2] = {0.f, 0.f};         // per-lane partial sums (reduced at end)

  // staging pointers (strength-reduced; advance per kt)
  const int srow  = lane>>3;
  const int sslot = (lane&7) ^ srow;
  const unsigned short* kgp = qkv + (size_t)b*TSEQ*3072 + 1024 + h*64
                              + (size_t)(w*8+srow)*3072 + sslot*8;
  const unsigned short* vgp = vt + (size_t)bh*64*TSEQ
                              + (size_t)(w*8+srow)*2048 + sslot*8;
  char* kd = (char*)ksm + w*1024 + lane*16;
  char* vd = (char*)vsm + w*1024 + lane*16;
  const float* mbp = mbias + (size_t)b*TSEQ + g*4;

  // read-side swizzle constants
  const int c3    = qv & 7;
  const int phys0 = (g ^ c3) << 4;           // linear slot ksi*4+g -> phys0 ^ (ksi<<6)
  const int pC    = (g>>1) ^ c3;             // P-write slot kk*2+(g>>1) -> ((kk*2)^pC)<<4
  char*       pWb = (char*)&ptile[w][0] + qv*128 + (g&1)*8;
  const char* pRb = (const char*)&ptile[w][0] + qv*128;

#define STAGE(buf)                                                    \
  { _Pragma("unroll")                                                 \
    for(int r_=0;r_<2;r_++){                                          \
      async_copy16(kd + (buf)*8192 + r_*4096, kgp + r_*98304);        \
      async_copy16(vd + (buf)*8192 + r_*4096, vgp + r_*65536);        \
    }                                                                 \
    kgp += 196608; vgp += 64; }

  STAGE(0);
  int cur = 0;

  for(int kt=0; kt<TSEQ/64; kt++){
    __syncthreads();                 // drains vmcnt(0): buf[cur] ready
    if(kt < TSEQ/64 - 1) STAGE(cur^1);   // prefetch overlaps this kt's compute

    f32x4 mbv[4];
    #pragma unroll
    for(int kk=0;kk<4;kk++) mbv[kk] = *(const f32x4*)(mbp + kk*16);
    mbp += 64;

    const char* kT = (const char*)ksm + cur*8192 + qv*128;
    const char* vT = (const char*)vsm + cur*8192 + qv*128;

    // K fragments once per kt, shared across both q-halves
    bf16x8 kf[2][4];
    #pragma unroll
    for(int ksi=0;ksi<2;ksi++)
      #pragma unroll
      for(int kk=0;kk<4;kk++)
        kf[ksi][kk] = *(const bf16x8*)(kT + kk*2048 + (phys0 ^ (ksi<<6)));

    #pragma unroll
    for(int t=0;t<2;t++){
      // S^T[key][q] = K · Q^T
      f32x4 s[4];
      #pragma unroll
      for(int kk=0;kk<4;kk++) s[kk]=zero4();
      __builtin_amdgcn_s_setprio(1);
      #pragma unroll
      for(int ksi=0;ksi<2;ksi++)
        #pragma unroll
        for(int kk=0;kk<4;kk++)
          s[kk] = mfma16(kf[ksi][kk], qf[t][ksi], s[kk]);
      __builtin_amdgcn_s_setprio(0);

      // softmax (log2 domain), in-place scale+bias, tree max
      #pragma unroll
      for(int kk=0;kk<4;kk++)
        #pragma unroll
        for(int r=0;r<4;r++)
          s[kk][r] = s[kk][r]*SC2F + mbv[kk][r];

      f32x4 mx;
      #pragma unroll
      for(int r=0;r<4;r++)
        mx[r] = fmaxf(fmaxf(s[0][r], s[1][r]), fmaxf(s[2][r], s[3][r]));
      float pm = fmaxf(fmaxf(mx[0], mx[1]), fmaxf(mx[2], mx[3]));
      pm = fmaxf(pm, __shfl_xor(pm, 16));
      pm = fmaxf(pm, __shfl_xor(pm, 32));

      float m2t = m2[t];
      if(!__all(pm - m2t <= 8.0f)){          // defer-max (T13, THR=8)
        float mn = fmaxf(m2t, pm);
        float sf = __builtin_amdgcn_exp2f(m2t - mn);
        lsum[t] *= sf;
        #pragma unroll
        for(int mi=0;mi<4;mi++){
          #pragma unroll
          for(int r=0;r<4;r++) oacc[mi][t][r] *= sf;
        }
        m2t = mn; m2[t] = mn;
      }

      float ps = 0.f;
      #pragma unroll
      for(int kk=0;kk<4;kk++){
        float p0 = __builtin_amdgcn_exp2f(s[kk][0]-m2t);
        float p1 = __builtin_amdgcn_exp2f(s[kk][1]-m2t);
        float p2 = __builtin_amdgcn_exp2f(s[kk][2]-m2t);
        float p3 = __builtin_amdgcn_exp2f(s[kk][3]-m2t);
        ps += (p0+p1)+(p2+p3);
        uint2 wv; wv.x = cvtpk(p0, p1); wv.y = cvtpk(p2, p3);
        *(uint2*)(pWb + (((kk*2) ^ pC) << 4)) = wv;
      }
      lsum[t] += ps;                         // cross-lane reduce deferred to epilogue

      asm volatile("" ::: "memory");   // order in-wave P writes before P reads

      // O^T[d][q] += V^T · P^T for this q-half
      __builtin_amdgcn_s_setprio(1);
      #pragma unroll
      for(int ksi=0;ksi<2;ksi++){
        bf16x8 pb = *(const bf16x8*)(pRb + (phys0 ^ (ksi<<6)));
        #pragma unroll
        for(int mi=0;mi<4;mi++){
          bf16x8 av = *(const bf16x8*)(vT + mi*2048 + (phys0 ^ (ksi<<6)));
          oacc[mi][t] = mfma16(av, pb, oacc[mi][t]);
        }
      }
      __builtin_amdgcn_s_setprio(0);
      asm volatile("" ::: "memory");   // order P reads before next half's P writes
    }
    cur ^= 1;
  }
#undef STAGE

  #pragma unroll
  for(int t=0;t<2;t++){
    float l = lsum[t];
    l += __shfl_xor(l, 16);
    l += __shfl_xor(l, 32);
    float inv = 1.0f / l;
    unsigned short* crow = cout + (size_t)(b*TSEQ + qb + w*32 + t*16 + qv)*1024 + h*64;
    #pragma unroll
    for(int mi=0;mi<4;mi++){
      uint2 o;
      o.x = cvtpk(oacc[mi][t][0]*inv, oacc[mi][t][1]*inv);
      o.y = cvtpk(oacc[mi][t][2]*inv, oacc[mi][t][3]*inv);
      *(uint2*)(crow + mi*16 + g*4) = o;
    }
  }
}

extern "C" void kernel_launch(void* const* d_in, const int* in_sizes, int n_in,
                              void* d_out, int out_size, void* d_ws, size_t ws_size,
                              hipStream_t stream){
  const float* x    = (const float*)d_in[0];
  const int*   am   = (const int*)  d_in[1];
  const float* ln_g = (const float*)d_in[2];
  const float* ln_b = (const float*)d_in[3];
  const float* Wq   = (const float*)d_in[4];
  const float* bq   = (const float*)d_in[5];
  const float* Wk   = (const float*)d_in[6];
  const float* bk   = (const float*)d_in[7];
  const float* Wv   = (const float*)d_in[8];
  const float* bv   = (const float*)d_in[9];
  const float* Wo   = (const float*)d_in[10];
  const float* bo   = (const float*)d_in[11];
  float* out = (float*)d_out;

  char* ws = (char*)d_ws;
  unsigned short* hb       = (unsigned short*)(ws);                         // 16MB
  unsigned short* wpack    = (unsigned short*)(ws + ((size_t)16<<20));      // 8MB
  float*          biaspack = (float*)         (ws + ((size_t)24<<20));      // 12KB
  float*          mbias    = (float*)         (ws + ((size_t)24<<20) + (64<<10)); // 32KB
  unsigned short* qkv      = (unsigned short*)(ws + ((size_t)25<<20));      // 48MB
  unsigned short* vt       = (unsigned short*)(ws + ((size_t)73<<20));      // 16MB

  ln_kernel<<<8192, 256, 0, stream>>>(x, ln_g, ln_b, hb);
  prep_w  <<<4096, 256, 0, stream>>>(Wq, Wk, Wv, Wo, wpack);
  prep2   <<<32,   256, 0, stream>>>(bq, bk, bv, am, biaspack, mbias);
  gemm_bt<0><<<dim3(24,64), 256, 0, stream>>>(hb, wpack, biaspack, nullptr, qkv, 3072);
  vtrans  <<<dim3(32,64), 256, 0, stream>>>(qkv, vt);
  attn_kernel<<<dim3(64,16), 256, 0, stream>>>(qkv, vt, mbias, hb);
  gemm_bt<1><<<dim3(8,64), 256, 0, stream>>>(hb, wpack + ((size_t)3<<20), bo, x, out, 1024);
}